// Round 1
// baseline (119.998 us; speedup 1.0000x reference)
//
#include <hip/hip_runtime.h>
#include <hip/hip_bf16.h>
#include <hip/hip_fp16.h>

// Problem constants (fixed by setup_inputs)
#define NROWS 4096
#define IDIM  512
#define HDIM  2048
#define ODIM  512
#define NG    8      // groups (prefix structure)
#define NCH   8      // H chunks
#define HC    256    // H per chunk
#define TM    64     // rows per main block

typedef __attribute__((ext_vector_type(8))) short short8;   // 8 bf16
typedef __attribute__((ext_vector_type(4))) float f32x4;

__device__ __forceinline__ unsigned short f2bf(float f) {
    unsigned int u = __float_as_uint(f);
    unsigned int r = (u + 0x7fffu + ((u >> 16) & 1u)) >> 16;
    return (unsigned short)r;
}

// async global->LDS, 16B per lane; lds base must be wave-uniform (HW adds lane*16)
__device__ __forceinline__ void glds16(const unsigned short* g, unsigned short* l) {
    __builtin_amdgcn_global_load_lds(
        (const __attribute__((address_space(1))) unsigned int*)g,
        (__attribute__((address_space(3))) unsigned int*)l, 16, 0, 0);
}

// ---- Prep kernel: fused x-convert + W1/W2 transpose-convert ----
__global__ __launch_bounds__(256) void k_prep(const float* __restrict__ x,
                                              const float* __restrict__ W1,
                                              const float* __restrict__ W2,
                                              unsigned short* __restrict__ xb,
                                              unsigned short* __restrict__ w1t,
                                              unsigned short* __restrict__ w2t) {
    __shared__ float tile[64 * 68];
    const int bz = blockIdx.x;
    const int t = threadIdx.x;
    if (bz < 1024) {
        int gt = bz * 256 + t;                    // x: 262144 threads, 8 floats each
        const float4* src = reinterpret_cast<const float4*>(x) + (size_t)gt * 2;
        float4 a = src[0], b = src[1];
        unsigned short o[8] = { f2bf(a.x), f2bf(a.y), f2bf(a.z), f2bf(a.w),
                                f2bf(b.x), f2bf(b.y), f2bf(b.z), f2bf(b.w) };
        *reinterpret_cast<uint4*>(xb + (size_t)gt * 8) = *reinterpret_cast<uint4*>(o);
        return;
    }
    int b = bz - 1024;
    const float* in;
    unsigned short* out;
    int R, C, c0, r0;
    if (b < 256) {            // W1: 512x2048 -> w1t[2048][512]
        in = W1; out = w1t; R = 512; C = 2048;
        c0 = (b & 31) * 64; r0 = (b >> 5) * 64;
    } else {                  // W2: 2048x512 -> w2t[512][2048]
        b -= 256;
        in = W2; out = w2t; R = 2048; C = 512;
        c0 = (b & 7) * 64; r0 = (b >> 3) * 64;
    }
    const int tx = t & 15, ty = t >> 4;
    #pragma unroll
    for (int p = 0; p < 4; ++p) {
        int rr = p * 16 + ty;
        float4 v = *reinterpret_cast<const float4*>(&in[(size_t)(r0 + rr) * C + c0 + tx * 4]);
        tile[rr * 68 + tx * 4 + 0] = v.x;
        tile[rr * 68 + tx * 4 + 1] = v.y;
        tile[rr * 68 + tx * 4 + 2] = v.z;
        tile[rr * 68 + tx * 4 + 3] = v.w;
    }
    __syncthreads();
    #pragma unroll
    for (int p = 0; p < 4; ++p) {
        int rr = p * 16 + ty;
        int cc = tx * 4;
        ushort4 o;
        o.x = f2bf(tile[(cc + 0) * 68 + rr]);
        o.y = f2bf(tile[(cc + 1) * 68 + rr]);
        o.z = f2bf(tile[(cc + 2) * 68 + rr]);
        o.w = f2bf(tile[(cc + 3) * 68 + rr]);
        *reinterpret_cast<ushort4*>(&out[(size_t)(c0 + rr) * R + r0 + cc]) = o;
    }
}

// ---- Kernel 1: fused prefix-GEMM1^T + relu + GEMM2 partials (fp16) ----
// grid (8, 64) = 512 blocks (2/CU), 512 threads (8 waves). LDS 72KB.
// GEMM1 computed TRANSPOSED (D[h][sample]) so each lane's 4 C-regs are 4
// consecutive h at one sample -> packed ds_write_b64 into sH. Bias folded
// into acc init. W1 fragments load global->VGPR (disjoint per wave).
// Counted-vmcnt schedule (T4): per g, issue {sX glds(1), w1f(4), sW glds(4)};
// B1 waits vmcnt(4) only -> sX+w1f done, the 4 sW glds stay in flight across
// the barrier and drain under GEMM1+sH-pack; B2 waits vmcnt(0) (sW) before
// GEMM2. P-stores never drained explicitly (oldest ops, covered by B1's wait).
__global__ __launch_bounds__(512, 4) void k_main(const unsigned short* __restrict__ xb,   // [4096][512]
                                                 const unsigned short* __restrict__ w1t,  // [2048][512] = W1^T
                                                 const unsigned short* __restrict__ w2t,  // [512][2048] = W2^T
                                                 const float* __restrict__ b1,            // [2048]
                                                 __half* __restrict__ P) {                // [NCH][4096][512] fp16
    __shared__ unsigned short sX[64 * 64];        // x_g  [sample][k]  8KB  (swizzled ^row&7)
    __shared__ unsigned short sW[64 * 256];       // W2_g [j][k]      32KB  (swizzled ^(row>>1)&7)
    __shared__ unsigned short sH[64 * 256];       // h    [sample][h] 32KB  (swizzled ^row&7)

    const int chunk = blockIdx.x;                 // 0..7
    const int row0  = blockIdx.y * TM;
    const int hbase = chunk * HC;

    const int t    = threadIdx.x;
    const int lane = t & 63, wv = t >> 6;         // wave 0..7
    const int l16  = lane & 15, quad = lane >> 4;

    // bias for this lane's h rows: h_local = wv*32 + ct*16 + quad*4 + r
    // acc1 = S + b1 from the start (bias never re-added per g)
    f32x4 acc1[2][4];
    #pragma unroll
    for (int ct = 0; ct < 2; ++ct) {
        f32x4 bv;
        #pragma unroll
        for (int r = 0; r < 4; ++r)
            bv[r] = b1[hbase + wv * 32 + ct * 16 + quad * 4 + r];
        #pragma unroll
        for (int rt = 0; rt < 4; ++rt) acc1[ct][rt] = bv;
    }

    const int srow = t >> 3;                      // sX staging row (0..63)
    const int scb  = t & 7;                       // sX staging 16B-block
    const int rt2  = wv >> 1;                     // GEMM2 row-tile
    const int jb   = (wv & 1) * 32;               // GEMM2 col base
    __half* Pc = P + (size_t)chunk * (NROWS * ODIM);
    const unsigned short* w1p = w1t + (size_t)(hbase + wv * 32 + l16) * 512 + quad * 8;

    for (int g = 0; g < NG; ++g) {
        // B0: prev GEMM2 LDS reads done (lgkm only; P-stores stay in flight)
        asm volatile("s_waitcnt lgkmcnt(0)" ::: "memory");
        __builtin_amdgcn_s_barrier();
        __builtin_amdgcn_sched_barrier(0);

        // stage x_g (8KB), W1 frags (regs), W2_g (32KB) — in this issue order
        glds16(xb + (size_t)(row0 + srow) * 512 + g * 64 + ((scb ^ (srow & 7)) << 3),
               sX + (size_t)(t & ~63) * 8);
        short8 w1f[2][2];
        #pragma unroll
        for (int kst = 0; kst < 2; ++kst)
            #pragma unroll
            for (int ct = 0; ct < 2; ++ct)
                w1f[kst][ct] = *reinterpret_cast<const short8*>(
                    w1p + (size_t)ct * 16 * 512 + g * 64 + kst * 32);
        #pragma unroll
        for (int i = 0; i < 4; ++i) {
            int slot = i * 512 + t;               // 0..2047
            int jr = slot >> 5, cb = slot & 31;   // jr 0..63, cb 0..31
            glds16(w2t + (size_t)(g * 64 + jr) * 2048 + hbase + ((cb ^ ((jr >> 1) & 7)) << 3),
                   sW + (size_t)(slot & ~63) * 8);
        }
        // B1: sX + w1f complete (oldest 9 of 13); 4 sW glds remain in flight
        asm volatile("s_waitcnt vmcnt(4) lgkmcnt(0)" ::: "memory");
        __builtin_amdgcn_s_barrier();
        __builtin_amdgcn_sched_barrier(0);

        // ---- GEMM1^T: acc1 += W1_g(A) x x_g(B) -> D[h][sample] ----
        // (overlaps the in-flight sW loads)
        #pragma unroll
        for (int kst = 0; kst < 2; ++kst) {
            short8 xf[4];
            #pragma unroll
            for (int rt = 0; rt < 4; ++rt) {
                int row = rt * 16 + l16;
                xf[rt] = *reinterpret_cast<const short8*>(
                    &sX[row * 64 + (((kst * 4 + quad) ^ (row & 7)) << 3)]);
            }
            #pragma unroll
            for (int ct = 0; ct < 2; ++ct)
                #pragma unroll
                for (int rt = 0; rt < 4; ++rt)
                    acc1[ct][rt] = __builtin_amdgcn_mfma_f32_16x16x32_bf16(
                        w1f[kst][ct], xf[rt], acc1[ct][rt], 0, 0, 0);
        }

        // ---- h = relu(acc1) -> sH via v_cvt_pk_bf16_f32 (RNE) ----
        #pragma unroll
        for (int ct = 0; ct < 2; ++ct) {
            const int cb2 = wv * 4 + ct * 2 + (quad >> 1);  // 16B-block of h
            #pragma unroll
            for (int rt = 0; rt < 4; ++rt) {
                const int sample = rt * 16 + l16;
                float m0 = fmaxf(acc1[ct][rt][0], 0.f);
                float m1 = fmaxf(acc1[ct][rt][1], 0.f);
                float m2 = fmaxf(acc1[ct][rt][2], 0.f);
                float m3 = fmaxf(acc1[ct][rt][3], 0.f);
                unsigned int p0, p1;
                asm("v_cvt_pk_bf16_f32 %0, %1, %2" : "=v"(p0) : "v"(m0), "v"(m1));
                asm("v_cvt_pk_bf16_f32 %0, %1, %2" : "=v"(p1) : "v"(m2), "v"(m3));
                uint2 pk = { p0, p1 };
                *reinterpret_cast<uint2*>(
                    &sH[sample * 256 + ((cb2 ^ (sample & 7)) << 3) + (quad & 1) * 4]) = pk;
            }
        }
        // B2: sW glds drained + sH writes visible
        asm volatile("s_waitcnt vmcnt(0) lgkmcnt(0)" ::: "memory");
        __builtin_amdgcn_s_barrier();
        __builtin_amdgcn_sched_barrier(0);

        // ---- GEMM2: P_g = h @ W2_g  (K=256 -> 8 ksteps, 2 tiles/wave) ----
        // B rows mapped j = jb + 2*l16 + c so each lane's two j are adjacent
        // -> packed half2 P-store (4B, coalesced).
        f32x4 acc2[2];
        acc2[0] = 0.f; acc2[1] = 0.f;
        #pragma unroll
        for (int kst = 0; kst < 8; ++kst) {
            int arow = rt2 * 16 + l16;
            const short8 a = *reinterpret_cast<const short8*>(
                &sH[arow * 256 + (((kst * 4 + quad) ^ (arow & 7)) << 3)]);
            #pragma unroll
            for (int c = 0; c < 2; ++c) {
                int brow = jb + 2 * l16 + c;
                const short8 b = *reinterpret_cast<const short8*>(
                    &sW[brow * 256 + (((kst * 4 + quad) ^ ((brow >> 1) & 7)) << 3)]);
                acc2[c] = __builtin_amdgcn_mfma_f32_16x16x32_bf16(a, b, acc2[c], 0, 0, 0);
            }
        }
        #pragma unroll
        for (int r = 0; r < 4; ++r) {
            __half2 pk;
            pk.x = __float2half(acc2[0][r]);
            pk.y = __float2half(acc2[1][r]);
            *reinterpret_cast<__half2*>(
                &Pc[(size_t)(row0 + rt2 * 16 + quad * 4 + r) * 512 +
                    g * 64 + jb + 2 * l16]) = pk;
        }
    }
}

// ---- Kernel 2: out = sum_c P[c] + b2 ----
__global__ __launch_bounds__(256) void k_reduce(const __half* __restrict__ P,
                                                const float* __restrict__ b2,
                                                float* __restrict__ out) {
    int t = blockIdx.x * 256 + threadIdx.x;       // 524288 threads, 4 outputs each
    size_t f = (size_t)t * 4;
    int j = (int)(f & 511);
    float4 s = *reinterpret_cast<const float4*>(&b2[j]);
    #pragma unroll
    for (int c = 0; c < NCH; ++c) {
        const __half2* p = reinterpret_cast<const __half2*>(P + (size_t)c * (NROWS * ODIM) + f);
        float2 a = __half22float2(p[0]);
        float2 b = __half22float2(p[1]);
        s.x += a.x; s.y += a.y; s.z += b.x; s.w += b.y;
    }
    *reinterpret_cast<float4*>(&out[f]) = s;
}

extern "C" void kernel_launch(void* const* d_in, const int* in_sizes, int n_in,
                              void* d_out, int out_size, void* d_ws, size_t ws_size,
                              hipStream_t stream) {
    const float* x  = (const float*)d_in[0];
    const float* W1 = (const float*)d_in[1];
    const float* b1 = (const float*)d_in[2];
    const float* W2 = (const float*)d_in[3];
    const float* b2 = (const float*)d_in[4];
    float* out = (float*)d_out;

    unsigned short* xb  = (unsigned short*)d_ws;                          // 4 MB
    unsigned short* w1t = (unsigned short*)((char*)d_ws + (4u << 20));    // 2 MB
    unsigned short* w2t = (unsigned short*)((char*)d_ws + (6u << 20));    // 2 MB
    __half*         P   = (__half*)((char*)d_ws + (8u << 20));            // 32 MB fp16

    k_prep<<<1536, 256, 0, stream>>>(x, W1, W2, xb, w1t, w2t);
    k_main<<<dim3(NCH, NROWS / TM), 512, 0, stream>>>(xb, w1t, w2t, b1, P);
    k_reduce<<<2048, 256, 0, stream>>>(P, b2, out);
}